// Round 9
// baseline (790.423 us; speedup 1.0000x reference)
//
#include <hip/hip_runtime.h>

#define B_ 1024
#define T_ 366
#define NS_ 365
#define CD_ 24

__device__ __forceinline__ float sigm(float x) { return __fdividef(1.f, 1.f + __expf(-x)); }
__device__ __forceinline__ float rl(float v, int k) {
    return __int_as_float(__builtin_amdgcn_readlane(__float_as_int(v), k));
}

// Non-rematerializable 16B load: asm origin is opaque to the register allocator,
// so the result MUST stay in VGPRs (or spill — budget 256 w/ waves_per_eu(2,2) avoids that).
__device__ __forceinline__ float4 gld4(const float* p) {
    float4 r;
    asm volatile("global_load_dwordx4 %0, %1, off\n\ts_waitcnt vmcnt(0)"
                 : "=v"(r) : "v"(p) : "memory");
    return r;
}

// ---- pack: Wpk[e][32] = {w0..23, rad, bias}; Apk[r][32] = {w0..28, bias} ----
__global__ void mclstm_pack(const float* __restrict__ Wr, const float* __restrict__ br,
                            const float* __restrict__ Wp, const float* __restrict__ bp,
                            const float* __restrict__ Wc, const float* __restrict__ bc,
                            const float* __restrict__ Wa, const float* __restrict__ ba,
                            float* __restrict__ Wpk, float* __restrict__ Apk) {
    const int e = blockIdx.x * 64 + threadIdx.x;
    if (e < 576) {
#pragma unroll
        for (int k = 0; k < 24; ++k) Wpk[e * 32 + k] = Wr[e * 29 + k];
        Wpk[e * 32 + 24] = Wr[e * 29 + 25];
        Wpk[e * 32 + 25] = br[e];
#pragma unroll
        for (int k = 26; k < 32; ++k) Wpk[e * 32 + k] = 0.f;
    } else if (e < 625) {
        const int r = e - 576;
#pragma unroll
        for (int k = 0; k < 29; ++k)
            Apk[r * 32 + k] = (r < 24) ? Wp[r * 29 + k] : (r < 48) ? Wc[(r - 24) * 29 + k] : Wa[k];
        Apk[r * 32 + 29] = (r < 24) ? bp[r] : (r < 48) ? bc[r - 24] : ba[0];
        Apk[r * 32 + 30] = 0.f; Apk[r * 32 + 31] = 0.f;
    }
}

// ---- main: one chain per 128-thread block (2 waves); weights VGPR-resident via asm ----
__global__ __attribute__((amdgpu_flat_work_group_size(128, 128), amdgpu_waves_per_eu(2, 2)))
void mclstm_main(const float* __restrict__ X, const float* __restrict__ ORY,
                 const float* __restrict__ Wpk, const float* __restrict__ Apk,
                 const float* __restrict__ c2a, const float* __restrict__ g2y,
                 float* __restrict__ allday, float* __restrict__ Ccell,
                 float* __restrict__ Cconv)
{
    __shared__ float zb1[600], zb2[600];                   // row-major z, stride 25
    __shared__ alignas(16) float pb1[672], pb2[672];       // col-major scaled P, stride 28
    __shared__ alignas(16) float cbuf[24];
    __shared__ float cmb[24];

    const int tid = threadIdx.x;
    const int l = tid & 63;          // lane within wave
    const int wv = tid >> 6;         // wave 0/1
    const int b = blockIdx.x;

    // 4 register-resident redis rows: e = tid + 128j (asm loads -> no remat possible)
    float wrg[4][24], wrad[4], brg[4];
    int za[4];
#pragma unroll
    for (int j = 0; j < 4; ++j) {
        const int e = tid + 128 * j;
        const float* wp = Wpk + (size_t)e * 32;
#pragma unroll
        for (int q = 0; q < 6; ++q) {
            const float4 v = gld4(wp + 4 * q);
            wrg[j][4*q] = v.x; wrg[j][4*q+1] = v.y; wrg[j][4*q+2] = v.z; wrg[j][4*q+3] = v.w;
        }
        const float4 t = gld4(wp + 24);
        wrad[j] = t.x; brg[j] = t.y;
        za[j] = (e / 24) * 25 + (e % 24);
    }
    // union extra row: wave0 = redis row 512+l; wave1 = aux row min(l,48)
    float ext[32];
    {
        const float* p = (wv == 0) ? (Wpk + (size_t)(512 + l) * 32)
                                   : (Apk + (size_t)((l < 49) ? l : 48) * 32);
#pragma unroll
        for (int q = 0; q < 8; ++q) {
            const float4 v = gld4(p + 4 * q);
            ext[4*q] = v.x; ext[4*q+1] = v.y; ext[4*q+2] = v.z; ext[4*q+3] = v.w;
        }
    }
    const int za4 = ((512 + l) / 24) * 25 + ((512 + l) % 24);

    // all_day per-lane constants (C_new[c] lives in lane 2c)
    const bool even = ((l & 1) == 0) && (l < 48);
    const float c2 = even ? c2a[l >> 1] : 0.f;
    const float gy = (even && l >= 32) ? g2y[(l >> 1) - 16] : 0.f;

    const float* xrow = X + (size_t)b * T_ * 4;
    const float* orow = ORY + (size_t)b * T_ * 7;

    if (tid < 7) allday[(size_t)b * T_ * 7 + tid] = orow[tid];
    if (tid < 24) cbuf[tid] = 0.f;
    __syncthreads();

    float Ncum = 0.f, radp = 0.f;

    for (int u = 0; u <= NS_; ++u) {
        const bool do1 = (u < NS_), doCv = (u > 0);
        const int uu = do1 ? u : (NS_ - 1);
        const float rad = xrow[uu * 4 + 0];

        // broadcast C (LDS b128, same addr across lanes)
        float Cs[24];
#pragma unroll
        for (int q = 0; q < 6; ++q) {
            const float4 v = ((const float4*)cbuf)[q];
            Cs[4*q] = v.x; Cs[4*q+1] = v.y; Cs[4*q+2] = v.z; Cs[4*q+3] = v.w;
        }

        // ---- Phase A: shared dots; z1 = D + wrad*rad_u, z2 = D + wrad*rad_{u-1} ----
#pragma unroll
        for (int j = 0; j < 4; ++j) {
            float p0 = brg[j], p1 = 0.f, p2 = 0.f, p3 = 0.f;
#pragma unroll
            for (int k = 0; k < 24; k += 4) {
                p0 = fmaf(wrg[j][k],   Cs[k],   p0);
                p1 = fmaf(wrg[j][k+1], Cs[k+1], p1);
                p2 = fmaf(wrg[j][k+2], Cs[k+2], p2);
                p3 = fmaf(wrg[j][k+3], Cs[k+3], p3);
            }
            const float D = (p0 + p1) + (p2 + p3);
            if (do1)  zb1[za[j]] = fmaf(wrad[j], rad,  D);
            if (doCv) zb2[za[j]] = fmaf(wrad[j], radp, D);
        }

        if (wv == 0) {
            // 5th redis row (bias at ext[25], rad coeff at ext[24])
            float p0 = ext[25], p1 = 0.f, p2 = 0.f, p3 = 0.f;
#pragma unroll
            for (int k = 0; k < 24; k += 4) {
                p0 = fmaf(ext[k],   Cs[k],   p0);
                p1 = fmaf(ext[k+1], Cs[k+1], p1);
                p2 = fmaf(ext[k+2], Cs[k+2], p2);
                p3 = fmaf(ext[k+3], Cs[k+3], p3);
            }
            const float D = (p0 + p1) + (p2 + p3);
            if (do1)  zb1[za4] = fmaf(ext[24], rad,  D);
            if (doCv) zb2[za4] = fmaf(ext[24], radp, D);
        } else if (do1) {
            // aux row + in-wave part/cons/assim -> cmid
            const float tmx = xrow[uu * 4 + 1], tmn = xrow[uu * 4 + 2];
            Ncum += xrow[uu * 4 + 3];
            const float dvs = orow[uu * 7];
            const float tave = 0.5f * (tmx + tmn);
            const float clm = fminf(fmaxf(tave * 50.f, 10.f), 40.f);
            const float eff = 0.54f - (clm - 10.f) * (0.18f / 30.f);
            const float cpot = rad * (eff * (2.f * 0.5f / 3.6f * (12.f / 44.f)));

            float z = ext[29];
#pragma unroll
            for (int k = 0; k < 24; ++k) z = fmaf(ext[k], Cs[k], z);
            z = fmaf(ext[24], dvs, z);
            z = fmaf(ext[25], rad, z);
            z = fmaf(ext[26], tmx, z);
            z = fmaf(ext[27], tmn, z);
            z = fmaf(ext[28], Ncum, z);

            float pm = (l < 24) ? z : -1e30f;
#pragma unroll
            for (int o = 1; o < 32; o <<= 1) pm = fmaxf(pm, __shfl_xor(pm, o, 32));
            float pe = (l < 24) ? __expf(z - pm) : 0.f;
            float ps = pe;
#pragma unroll
            for (int o = 1; o < 32; o <<= 1) ps += __shfl_xor(ps, o, 32);
            const float conz = __shfl(z, 24 + (l & 31), 64);
            const float asmz = __shfl(z, 48, 64);
            if (l < 24) {
                const float part = __fdividef(pe, ps);
                const float cmv = cbuf[l];
                cmb[l] = (cmv + sigm(asmz) * cpot * part) * (1.f - sigm(conz));
            }
        }
        __syncthreads();   // B1: zb + cmid ready

        // ---- row softmax: 2 lanes/row; wave0=kind0, wave1=kind1; P stored col-major ----
        {
            const bool act = (l < 48) && ((wv == 0) ? do1 : doCv);
            if (act) {
                const int r = l >> 1, h = l & 1;
                const float* zs = (wv == 0) ? zb1 : zb2;
                float* pd = (wv == 0) ? pb1 : pb2;
                float z[12];
#pragma unroll
                for (int i = 0; i < 12; ++i) z[i] = zs[r * 25 + h * 12 + i];
                float m = z[0];
#pragma unroll
                for (int i = 1; i < 12; ++i) m = fmaxf(m, z[i]);
                m = fmaxf(m, __shfl_xor(m, 1));
                float s = 0.f;
#pragma unroll
                for (int i = 0; i < 12; ++i) { z[i] = __expf(z[i] - m); s += z[i]; }
                s += __shfl_xor(s, 1);
                const float mlt = (wv == 0) ? cmb[r] : cbuf[r];
                const float f = __fdividef(mlt, s);
#pragma unroll
                for (int i = 0; i < 12; ++i) pd[(h * 12 + i) * 28 + r] = z[i] * f;
            }
        }
        __syncthreads();   // B2: scaled P (col-major) ready

        // ---- colsum (2 lanes/col, b128) + outputs + folded all_day ----
        {
            const bool a0 = (wv == 0) && (l < 48) && do1;
            const bool a1 = (wv == 1) && (l < 48) && doCv;
            const int c = l >> 1, h = l & 1;
            float s = 0.f;
            if (a0 || a1) {
                const float* psrc = (wv == 0) ? pb1 : pb2;
                const float4* p4 = (const float4*)&psrc[c * 28 + h * 12];
#pragma unroll
                for (int i = 0; i < 3; ++i) {
                    const float4 v = p4[i];
                    s += (v.x + v.y) + (v.z + v.w);
                }
                s += __shfl_xor(s, 1);
            }
            if (a1 && h == 0) Cconv[((size_t)b * NS_ + (u - 1)) * CD_ + c] = s;
            if (a0 && h == 0) {
                cbuf[c] = s;
                Ccell[((size_t)b * NS_ + u) * CD_ + c] = s;
            }
            if (wv == 0 && do1) {
                const float cv = even ? s : 0.f;     // lane 2c holds C_new[c]
                const float pv = fabsf(cv * c2);
                const float yv = fabsf(cv * gy);
                float a16 = cv, p16 = pv, y16 = yv;
#pragma unroll
                for (int o = 1; o < 16; o <<= 1) {
                    a16 += __shfl_xor(a16, o, 16);
                    p16 += __shfl_xor(p16, o, 16);
                    y16 += __shfl_xor(y16, o, 16);
                }
                const float pai = rl(p16, 0) + rl(p16, 16) + rl(p16, 32);
                const float lea = rl(a16, 0)  * (1.f / 0.419f);
                const float ste = rl(a16, 16) * (1.f / 0.431f);
                const float gra = rl(a16, 32) * (1.f / 0.487f);
                const float yie = rl(y16, 32) * (1.f / 0.487f);
                const float agb = lea + ste + gra;
                const float dvsn = orow[(u + 1) * 7];
                if (l < 7) {
                    float val = dvsn;
                    val = (l == 1) ? pai : val;
                    val = (l == 2) ? lea : val;
                    val = (l == 3) ? ste : val;
                    val = (l == 4) ? gra : val;
                    val = (l == 5) ? agb : val;
                    val = (l == 6) ? yie : val;
                    allday[((size_t)b * T_ + (u + 1)) * 7 + l] = val;
                }
            }
        }
        __syncthreads();   // B3: C(t+1) visible
        radp = rad;
    }
}

extern "C" void kernel_launch(void* const* d_in, const int* in_sizes, int n_in,
                              void* d_out, int out_size, void* d_ws, size_t ws_size,
                              hipStream_t stream) {
    const float* X   = (const float*)d_in[0];
    const float* ORY = (const float*)d_in[1];
    const float* Wr  = (const float*)d_in[2];
    const float* br  = (const float*)d_in[3];
    const float* Wp  = (const float*)d_in[4];
    const float* bp  = (const float*)d_in[5];
    const float* Wc  = (const float*)d_in[6];
    const float* bc  = (const float*)d_in[7];
    const float* Wa  = (const float*)d_in[8];
    const float* ba  = (const float*)d_in[9];
    const float* c2a = (const float*)d_in[10];
    const float* g2y = (const float*)d_in[11];

    float* allday = (float*)d_out;
    float* Ccell  = allday + (size_t)B_ * T_ * 7;
    float* Cconv  = Ccell + (size_t)B_ * NS_ * CD_;

    float* Wpk = (float*)d_ws;            // 576*32 floats
    float* Apk = Wpk + 576 * 32;          // 49*32 floats

    hipLaunchKernelGGL(mclstm_pack, dim3(10), dim3(64), 0, stream,
                       Wr, br, Wp, bp, Wc, bc, Wa, ba, Wpk, Apk);
    hipLaunchKernelGGL(mclstm_main, dim3(B_), dim3(128), 0, stream,
                       X, ORY, Wpk, Apk, c2a, g2y, allday, Ccell, Cconv);
}